// Round 4
// baseline (345.387 us; speedup 1.0000x reference)
//
#include <hip/hip_runtime.h>
#include <math.h>

#define HID 64
#define BN_EPS 1e-5f
#define NREP 64   // stats replica slots (contention: nblocks/NREP per address)

typedef unsigned int uint;
typedef unsigned short ushort;

// ============ bf16 helpers ============

__device__ inline uint bf16pk(float a, float b) {
    uint ua = __builtin_bit_cast(uint, a);
    ua += 0x7fff + ((ua >> 16) & 1);
    uint ub = __builtin_bit_cast(uint, b);
    ub += 0x7fff + ((ub >> 16) & 1);
    return (ua >> 16) | (ub & 0xffff0000u);
}
__device__ inline float bfl(uint v) { return __builtin_bit_cast(float, v << 16); }
__device__ inline float bfh(uint v) { return __builtin_bit_cast(float, v & 0xffff0000u); }

// ============ graph build: direct atomic degree count (+ overlapped x-stats) ============
// blocks [0,DB): deg histograms via global atomics (~16 adds/address, low contention)
// blocks [DB,..): BN stats stage-1 over x -> replica slots of statsX

__global__ __launch_bounds__(256) void k_deg_stats(const int* __restrict__ ei, int E, int DB,
                                                   int* __restrict__ deg_d, int* __restrict__ deg_s,
                                                   const float* __restrict__ X, int n,
                                                   float* __restrict__ stats) {
    __shared__ __align__(16) char smemraw[8192];
    int t = threadIdx.x;
    if ((int)blockIdx.x < DB) {
        int stride = DB * 256;
        for (int e = blockIdx.x * 256 + t; e < E; e += stride) {
            int src = ei[e], dst = ei[E + e];
            atomicAdd(&deg_s[src], 1);
            atomicAdd(&deg_d[dst], 1);
        }
    } else {
        // BN stats stage-1 over x [n,128] -> replica slot (bid & 63): [0..127]=sum, [128..255]=sumsq
        int b = blockIdx.x - DB;
        int SB = gridDim.x - DB;
        float4* shs = (float4*)smemraw;     // 256 float4 = 4KB
        float4* shq = shs + 256;            // 4KB more
        int c4 = t & 31, rsub = t >> 5;
        float4 s = make_float4(0.f, 0.f, 0.f, 0.f);
        float4 q = make_float4(0.f, 0.f, 0.f, 0.f);
        for (int r = b * 8 + rsub; r < n; r += SB * 8) {
            float4 v = ((const float4*)X)[(size_t)r * 32 + c4];
            s.x += v.x; s.y += v.y; s.z += v.z; s.w += v.w;
            q.x = fmaf(v.x, v.x, q.x); q.y = fmaf(v.y, v.y, q.y);
            q.z = fmaf(v.z, v.z, q.z); q.w = fmaf(v.w, v.w, q.w);
        }
        shs[t] = s; shq[t] = q;
        __syncthreads();
        if (rsub == 0) {
            #pragma unroll
            for (int k = 1; k < 8; k++) {
                float4 a = shs[t + k * 32], bq = shq[t + k * 32];
                s.x += a.x; s.y += a.y; s.z += a.z; s.w += a.w;
                q.x += bq.x; q.y += bq.y; q.z += bq.z; q.w += bq.w;
            }
            float* sb = stats + ((int)blockIdx.x & (NREP - 1)) * 256;
            atomicAdd(&sb[4 * t + 0], s.x); atomicAdd(&sb[4 * t + 1], s.y);
            atomicAdd(&sb[4 * t + 2], s.z); atomicAdd(&sb[4 * t + 3], s.w);
            atomicAdd(&sb[128 + 4 * t + 0], q.x); atomicAdd(&sb[128 + 4 * t + 1], q.y);
            atomicAdd(&sb[128 + 4 * t + 2], q.z); atomicAdd(&sb[128 + 4 * t + 3], q.w);
        }
    }
}

// ============ single-pass decoupled-lookback scan over deg_d -> rowptr/cursor,
//              plus dis = rsqrt(deg_s+1). 1024 elements/block (int4 per thread). ============

__global__ __launch_bounds__(256) void k_scan_dis(const int* __restrict__ deg_d,
                                                  const int* __restrict__ deg_s,
                                                  int N, int E,
                                                  int* __restrict__ rowptr, int* __restrict__ cursor,
                                                  float* __restrict__ dis,
                                                  int* __restrict__ aggr, int* __restrict__ flag) {
    __shared__ int sh[256];
    __shared__ int s_base;
    int t = threadIdx.x, b = blockIdx.x;
    int base_el = b * 1024 + t * 4;

    // dis (deg arrays are padded past N; writes guarded)
    int4 ds = *(const int4*)(deg_s + base_el);
    float4 dv;
    dv.x = rsqrtf((float)(ds.x + 1)); dv.y = rsqrtf((float)(ds.y + 1));
    dv.z = rsqrtf((float)(ds.z + 1)); dv.w = rsqrtf((float)(ds.w + 1));
    if (base_el + 3 < N) *(float4*)(dis + base_el) = dv;
    else {
        if (base_el + 0 < N) dis[base_el + 0] = dv.x;
        if (base_el + 1 < N) dis[base_el + 1] = dv.y;
        if (base_el + 2 < N) dis[base_el + 2] = dv.z;
        if (base_el + 3 < N) dis[base_el + 3] = dv.w;
    }

    // local prefix
    int4 d = *(const int4*)(deg_d + base_el);
    int s3 = d.x + d.y + d.z + d.w;
    sh[t] = s3;
    __syncthreads();
    for (int off = 1; off < 256; off <<= 1) {
        int u = (t >= off) ? sh[t - off] : 0;
        __syncthreads();
        sh[t] += u;
        __syncthreads();
    }
    int excl_thread = sh[t] - s3;
    int block_total = sh[255];

    // publish aggregate, then lookback over predecessors
    if (t == 0) {
        s_base = 0;
        atomicExch(&aggr[b], block_total);
        __threadfence();
        atomicExch(&flag[b], 1);
    }
    __syncthreads();
    int lb = 0;
    for (int p = t; p < b; p += 256) {
        while (atomicAdd(&flag[p], 0) == 0) { __builtin_amdgcn_s_sleep(2); }
        lb += atomicAdd(&aggr[p], 0);
    }
    if (lb) atomicAdd(&s_base, lb);
    __syncthreads();

    int base = s_base + excl_thread;
    int r0 = base, r1 = r0 + d.x, r2 = r1 + d.y, r3 = r2 + d.z;
    if (base_el + 3 < N) {
        *(int4*)(rowptr + base_el) = make_int4(r0, r1, r2, r3);
        *(int4*)(cursor + base_el) = make_int4(r0, r1, r2, r3);
    } else {
        if (base_el + 0 < N) { rowptr[base_el + 0] = r0; cursor[base_el + 0] = r0; }
        if (base_el + 1 < N) { rowptr[base_el + 1] = r1; cursor[base_el + 1] = r1; }
        if (base_el + 2 < N) { rowptr[base_el + 2] = r2; cursor[base_el + 2] = r2; }
        if (base_el + 3 < N) { rowptr[base_el + 3] = r3; cursor[base_el + 3] = r3; }
    }
    if (b == (int)gridDim.x - 1 && t == 255) rowptr[N] = E;
}

// ============ CSR fill: scatter src into dst rows (order within row arbitrary) ============

__global__ __launch_bounds__(256) void k_fill(const int* __restrict__ ei, int E,
                                              int* __restrict__ cursor, int* __restrict__ eidx) {
    int stride = gridDim.x * 256;
    for (int e = blockIdx.x * 256 + threadIdx.x; e < E; e += stride) {
        int src = ei[e], dst = ei[E + e];
        int pos = atomicAdd(&cursor[dst], 1);
        eidx[pos] = src;
    }
}

// ============ GEMM with fused BN-fold prologue (replica-summed stats)
//              + optional replica-atomic stats epilogue ============

template <int K, bool RELU, bool DIS, bool STATS, bool HASB>
__global__ __launch_bounds__(256) void k_gemm(const float* __restrict__ X, const float* __restrict__ W,
                                              const float* __restrict__ stats,
                                              const float* __restrict__ gamma, const float* __restrict__ beta,
                                              const float* __restrict__ bias0, const float* __restrict__ dis,
                                              float n_inv, void* __restrict__ out, int n,
                                              float* __restrict__ sout) {
    constexpr int KC = 64;
    constexpr int XS = 68;
    __shared__ float Xs[KC * XS];
    __shared__ float Wsm[KC * HID];
    __shared__ float As[128], Cs[128];

    int t = threadIdx.x;
    int tx = t & 15, ty = t >> 4;
    int row0 = blockIdx.x * 64;

    if (t < K) {
        // sum the NREP replica slots (L2-hot; stride 2K floats per replica)
        float ssum = 0.f, qsum = 0.f;
        const float* sp = stats + t;
        #pragma unroll 8
        for (int r = 0; r < NREP; ++r) {
            ssum += sp[(size_t)r * 2 * K];
            qsum += sp[(size_t)r * 2 * K + K];
        }
        float mu = ssum * n_inv;
        float var = qsum * n_inv - mu * mu;
        float a = gamma[t] * rsqrtf(var + BN_EPS);
        As[t] = a;
        Cs[t] = beta[t] - mu * a;
    }
    __syncthreads();

    float acc[4][4];
    #pragma unroll
    for (int i = 0; i < 4; i++)
        #pragma unroll
        for (int j = 0; j < 4; j++) acc[i][j] = 0.f;
    float4 bp = make_float4(0.f, 0.f, 0.f, 0.f);

    for (int kc = 0; kc < K; kc += KC) {
        #pragma unroll
        for (int it = 0; it < 4; ++it) {
            int id = t + 256 * it;
            int r = id >> 4, c4 = id & 15;
            float4 v = make_float4(0.f, 0.f, 0.f, 0.f);
            if (row0 + r < n) v = *(const float4*)(X + (size_t)(row0 + r) * K + kc + 4 * c4);
            int kk = 4 * c4;
            Xs[(kk + 0) * XS + r] = v.x;
            Xs[(kk + 1) * XS + r] = v.y;
            Xs[(kk + 2) * XS + r] = v.z;
            Xs[(kk + 3) * XS + r] = v.w;
        }
        {
            const float4* wsrc = (const float4*)(W + (size_t)kc * HID);
            #pragma unroll
            for (int it = 0; it < 4; ++it) {
                int id = t + 256 * it;
                int kl = id >> 4;
                float4 raw = wsrc[id];
                float a = As[kc + kl], c = Cs[kc + kl];
                float4 sc;
                sc.x = a * raw.x; sc.y = a * raw.y; sc.z = a * raw.z; sc.w = a * raw.w;
                ((float4*)Wsm)[id] = sc;
                bp.x = fmaf(c, raw.x, bp.x);
                bp.y = fmaf(c, raw.y, bp.y);
                bp.z = fmaf(c, raw.z, bp.z);
                bp.w = fmaf(c, raw.w, bp.w);
            }
        }
        __syncthreads();
        #pragma unroll 8
        for (int k = 0; k < KC; ++k) {
            float4 xv = *(const float4*)&Xs[k * XS + 4 * ty];
            float4 wv = *(const float4*)&Wsm[k * HID + 4 * tx];
            acc[0][0] = fmaf(xv.x, wv.x, acc[0][0]);
            acc[0][1] = fmaf(xv.x, wv.y, acc[0][1]);
            acc[0][2] = fmaf(xv.x, wv.z, acc[0][2]);
            acc[0][3] = fmaf(xv.x, wv.w, acc[0][3]);
            acc[1][0] = fmaf(xv.y, wv.x, acc[1][0]);
            acc[1][1] = fmaf(xv.y, wv.y, acc[1][1]);
            acc[1][2] = fmaf(xv.y, wv.z, acc[1][2]);
            acc[1][3] = fmaf(xv.y, wv.w, acc[1][3]);
            acc[2][0] = fmaf(xv.z, wv.x, acc[2][0]);
            acc[2][1] = fmaf(xv.z, wv.y, acc[2][1]);
            acc[2][2] = fmaf(xv.z, wv.z, acc[2][2]);
            acc[2][3] = fmaf(xv.z, wv.w, acc[2][3]);
            acc[3][0] = fmaf(xv.w, wv.x, acc[3][0]);
            acc[3][1] = fmaf(xv.w, wv.y, acc[3][1]);
            acc[3][2] = fmaf(xv.w, wv.z, acc[3][2]);
            acc[3][3] = fmaf(xv.w, wv.w, acc[3][3]);
        }
        __syncthreads();
    }

    {
        float* redb = Xs + 2048;
        *(float4*)&redb[ty * 64 + 4 * tx] = bp;
        __syncthreads();
        if (t < 64) {
            float s = 0.f;
            #pragma unroll
            for (int k = 0; k < 16; ++k) s += redb[k * 64 + t];
            Xs[3072 + t] = s + (HASB ? bias0[t] : 0.f);
        }
        __syncthreads();
    }
    float4 bv = *(const float4*)&Xs[3072 + 4 * tx];

    float4 cs = make_float4(0.f, 0.f, 0.f, 0.f);
    float4 cq = make_float4(0.f, 0.f, 0.f, 0.f);
    #pragma unroll
    for (int i = 0; i < 4; ++i) {
        int row = row0 + 4 * ty + i;
        bool valid = row < n;
        float vx = acc[i][0] + bv.x, vy = acc[i][1] + bv.y;
        float vz = acc[i][2] + bv.z, vw = acc[i][3] + bv.w;
        if constexpr (DIS) {
            if (valid) {
                float d = dis[row];
                uint2 pk;
                pk.x = bf16pk(vx * d, vy * d);
                pk.y = bf16pk(vz * d, vw * d);
                *(uint2*)((ushort*)out + (size_t)row * HID + 4 * tx) = pk;
            }
        } else {
            float4 v;
            v.x = RELU ? fmaxf(vx, 0.f) : vx;
            v.y = RELU ? fmaxf(vy, 0.f) : vy;
            v.z = RELU ? fmaxf(vz, 0.f) : vz;
            v.w = RELU ? fmaxf(vw, 0.f) : vw;
            if (valid) {
                *(float4*)((float*)out + (size_t)row * HID + 4 * tx) = v;
                if constexpr (STATS) {
                    cs.x += v.x; cs.y += v.y; cs.z += v.z; cs.w += v.w;
                    cq.x = fmaf(v.x, v.x, cq.x); cq.y = fmaf(v.y, v.y, cq.y);
                    cq.z = fmaf(v.z, v.z, cq.z); cq.w = fmaf(v.w, v.w, cq.w);
                }
            }
        }
    }
    if constexpr (STATS) {
        __syncthreads();
        float* reds = Xs;
        float* redq = Xs + 1024;
        *(float4*)&reds[ty * 64 + 4 * tx] = cs;
        *(float4*)&redq[ty * 64 + 4 * tx] = cq;
        __syncthreads();
        if (t < 64) {
            float s = 0.f, q = 0.f;
            #pragma unroll
            for (int k = 0; k < 16; ++k) { s += reds[k * 64 + t]; q += redq[k * 64 + t]; }
            float* sb = sout + ((int)blockIdx.x & (NREP - 1)) * 128;
            atomicAdd(&sb[t], s);
            atomicAdd(&sb[64 + t], q);
        }
    }
}

// ============ aggregation: 8 nodes/block, per node 4 edge-slots x 8 feature-lanes,
// 16B uint4 gathers, branch-free batches of 4 edges per slot (4 gathers in flight
// per lane; masked lanes gather the cache-hot self row with weight 0).
// !POOL: writes fp32 out rows + replica-atomic BN stats. POOL: fuses global_add_pool. ============

template <bool POOL>
__global__ __launch_bounds__(256) void k_agg(const ushort* __restrict__ s, const int* __restrict__ rowptr,
                                             const int* __restrict__ eidx, const float* __restrict__ dis,
                                             const float* __restrict__ bias, float* __restrict__ out, int n,
                                             float* __restrict__ sout, const int* __restrict__ batch,
                                             float* __restrict__ pool_out) {
    __shared__ float shs[8 * 64];
    __shared__ float shq[8 * 64];
    __shared__ int ib[8];
    int t = threadIdx.x;
    int nl = t >> 5;          // node slot in block (0..7); 2 nodes per wave
    int li = t & 31;
    int slot = li >> 3;       // edge slot 0..3
    int c = li & 7;           // uint4 column -> features 8c..8c+7
    int i = blockIdx.x * 8 + nl;
    const uint4* sp4 = (const uint4*)s;
    float a[8];
    #pragma unroll
    for (int k = 0; k < 8; ++k) a[k] = 0.f;
    bool valid = i < n;
    if (valid) {
        int qe = rowptr[i + 1];
        int q = rowptr[i] + slot;
        while (q < qe) {
            // branch-free batch of 4 edges for this slot (stride 4 between slots)
            int qm = qe - 1;
            int q1 = q + 4, q2 = q + 8, q3 = q + 12;
            bool p1 = q1 < qe, p2 = q2 < qe, p3 = q3 < qe;
            int j0 = eidx[q];
            int j1 = eidx[min(q1, qm)];
            int j2 = eidx[min(q2, qm)];
            int j3 = eidx[min(q3, qm)];
            if (!p1) j1 = i;           // masked -> self row (L1-hot), weight 0
            if (!p2) j2 = i;
            if (!p3) j3 = i;
            uint4 v0 = sp4[(size_t)j0 * 8 + c];
            uint4 v1 = sp4[(size_t)j1 * 8 + c];
            uint4 v2 = sp4[(size_t)j2 * 8 + c];
            uint4 v3 = sp4[(size_t)j3 * 8 + c];
            float m1 = p1 ? 1.f : 0.f;
            float m2 = p2 ? 1.f : 0.f;
            float m3 = p3 ? 1.f : 0.f;
            q += 16;
            a[0] += bfl(v0.x); a[1] += bfh(v0.x);
            a[2] += bfl(v0.y); a[3] += bfh(v0.y);
            a[4] += bfl(v0.z); a[5] += bfh(v0.z);
            a[6] += bfl(v0.w); a[7] += bfh(v0.w);
            a[0] = fmaf(m1, bfl(v1.x), a[0]); a[1] = fmaf(m1, bfh(v1.x), a[1]);
            a[2] = fmaf(m1, bfl(v1.y), a[2]); a[3] = fmaf(m1, bfh(v1.y), a[3]);
            a[4] = fmaf(m1, bfl(v1.z), a[4]); a[5] = fmaf(m1, bfh(v1.z), a[5]);
            a[6] = fmaf(m1, bfl(v1.w), a[6]); a[7] = fmaf(m1, bfh(v1.w), a[7]);
            a[0] = fmaf(m2, bfl(v2.x), a[0]); a[1] = fmaf(m2, bfh(v2.x), a[1]);
            a[2] = fmaf(m2, bfl(v2.y), a[2]); a[3] = fmaf(m2, bfh(v2.y), a[3]);
            a[4] = fmaf(m2, bfl(v2.z), a[4]); a[5] = fmaf(m2, bfh(v2.z), a[5]);
            a[6] = fmaf(m2, bfl(v2.w), a[6]); a[7] = fmaf(m2, bfh(v2.w), a[7]);
            a[0] = fmaf(m3, bfl(v3.x), a[0]); a[1] = fmaf(m3, bfh(v3.x), a[1]);
            a[2] = fmaf(m3, bfl(v3.y), a[2]); a[3] = fmaf(m3, bfh(v3.y), a[3]);
            a[4] = fmaf(m3, bfl(v3.z), a[4]); a[5] = fmaf(m3, bfh(v3.z), a[5]);
            a[6] = fmaf(m3, bfl(v3.w), a[6]); a[7] = fmaf(m3, bfh(v3.w), a[7]);
        }
    }
    // reduce across the 4 edge slots (lanes differ in bits 3,4 -> stays within node group)
    #pragma unroll
    for (int k = 0; k < 8; ++k) a[k] += __shfl_xor(a[k], 8);
    #pragma unroll
    for (int k = 0; k < 8; ++k) a[k] += __shfl_xor(a[k], 16);

    if (li < 8) {
        float r[8];
        if (valid) {
            uint4 v = sp4[(size_t)i * 8 + c];   // self-loop contribution
            a[0] += bfl(v.x); a[1] += bfh(v.x);
            a[2] += bfl(v.y); a[3] += bfh(v.y);
            a[4] += bfl(v.z); a[5] += bfh(v.z);
            a[6] += bfl(v.w); a[7] += bfh(v.w);
            float d = dis[i];
            float4 b0 = *(const float4*)(bias + 8 * c);
            float4 b1 = *(const float4*)(bias + 8 * c + 4);
            r[0] = fmaxf(fmaf(d, a[0], b0.x), 0.f);
            r[1] = fmaxf(fmaf(d, a[1], b0.y), 0.f);
            r[2] = fmaxf(fmaf(d, a[2], b0.z), 0.f);
            r[3] = fmaxf(fmaf(d, a[3], b0.w), 0.f);
            r[4] = fmaxf(fmaf(d, a[4], b1.x), 0.f);
            r[5] = fmaxf(fmaf(d, a[5], b1.y), 0.f);
            r[6] = fmaxf(fmaf(d, a[6], b1.z), 0.f);
            r[7] = fmaxf(fmaf(d, a[7], b1.w), 0.f);
            if constexpr (!POOL) {
                *(float4*)(out + (size_t)i * HID + 8 * c)     = make_float4(r[0], r[1], r[2], r[3]);
                *(float4*)(out + (size_t)i * HID + 8 * c + 4) = make_float4(r[4], r[5], r[6], r[7]);
            }
        } else {
            #pragma unroll
            for (int k = 0; k < 8; ++k) r[k] = 0.f;
        }
        #pragma unroll
        for (int k = 0; k < 8; ++k) shs[nl * 64 + 8 * c + k] = r[k];
        if constexpr (!POOL) {
            #pragma unroll
            for (int k = 0; k < 8; ++k) shq[nl * 64 + 8 * c + k] = r[k] * r[k];
        }
    }
    if constexpr (POOL) {
        if (li == 0) ib[nl] = valid ? batch[i] : -1;
    }
    __syncthreads();
    if (t < 64) {
        if constexpr (!POOL) {
            float ss = 0.f, qq = 0.f;
            #pragma unroll
            for (int k = 0; k < 8; ++k) { ss += shs[k * 64 + t]; qq += shq[k * 64 + t]; }
            float* sb = sout + ((int)blockIdx.x & (NREP - 1)) * 128;
            atomicAdd(&sb[t], ss);
            atomicAdd(&sb[64 + t], qq);
        } else {
            // batch is sorted -> run-length merge across the 8 nodes, then few atomics
            int g = ib[0];
            float run = shs[t];
            #pragma unroll
            for (int k = 1; k < 8; ++k) {
                int gk = ib[k];
                float v = shs[k * 64 + t];
                if (gk == g) {
                    run += v;
                } else {
                    if (g >= 0) atomicAdd(&pool_out[(size_t)g * HID + t], run);
                    g = gk; run = v;
                }
            }
            if (g >= 0) atomicAdd(&pool_out[(size_t)g * HID + t], run);
        }
    }
}

// ============ driver ============

extern "C" void kernel_launch(void* const* d_in, const int* in_sizes, int n_in,
                              void* d_out, int out_size, void* d_ws, size_t ws_size,
                              hipStream_t stream) {
    const float* x     = (const float*)d_in[0];
    const int*   ei    = (const int*)d_in[1];
    const int*   batch = (const int*)d_in[2];
    const float* bnfg  = (const float*)d_in[3];
    const float* bnfb  = (const float*)d_in[4];
    const float* Wfeat = (const float*)d_in[5];
    const float* bfeat = (const float*)d_in[6];
    const float* bng   = (const float*)d_in[7];
    const float* bnb   = (const float*)d_in[8];
    const float* Ws    = (const float*)d_in[9];
    const float* bs    = (const float*)d_in[10];
    float* out = (float*)d_out;

    const int N   = in_sizes[2];
    const int E   = in_sizes[1] / 2;
    const int L   = in_sizes[9] / (HID * HID);
    const int DB  = 512;                    // degree-count blocks
    const int SB  = 512;                    // stats<128> stage-1 blocks
    const int SC  = (N + 1023) / 1024;      // scan blocks (1024 elements each)
    const int FB  = 1024;                   // fill blocks
    const int gG  = (N + 63) / 64;          // gemm blocks
    const int gA  = (N + 7) / 8;            // agg blocks
    const float n_inv = 1.f / (float)N;

    char* w = (char*)d_ws;
    auto alloc = [&](size_t bytes) { char* p = w; w += (bytes + 255) & ~(size_t)255; return p; };
    // ---- zeroed prefix ----
    int*   deg_d  = (int*)alloc(((size_t)N + 1024) * 4);   // padded for int4 tail reads
    int*   deg_s  = (int*)alloc(((size_t)N + 1024) * 4);
    int*   aggr   = (int*)alloc(256 * 4);                  // scan lookback aggregates
    int*   flag   = (int*)alloc(256 * 4);                  // scan lookback flags
    // statsX: NREP replicas x (sum128, sq128) for the x BN
    float* statsX = (float*)alloc((size_t)NREP * 256 * 4);
    // statsL: 3 layer slots, each NREP replicas x (sum64, sq64)
    float* statsL = (float*)alloc((size_t)3 * NREP * 128 * 4);
    size_t zero_bytes = (size_t)(w - (char*)d_ws);
    // ---- rest ----
    int*   rowptr = (int*)alloc(((size_t)N + 1024) * 4);   // padded for int4 writes
    int*   cursor = (int*)alloc(((size_t)N + 1024) * 4);
    int*   eidx   = (int*)alloc((size_t)E * 4);
    float* dis    = (float*)alloc((size_t)N * 4);
    float* bufA   = (float*)alloc((size_t)N * HID * 4);
    ushort* bufB  = (ushort*)alloc((size_t)N * HID * 2);

    hipMemsetAsync(d_ws, 0, zero_bytes, stream);
    hipMemsetAsync(d_out, 0, (size_t)out_size * sizeof(float), stream);  // pool accumulates atomically

    // graph build: degrees (+ overlapped x-stats) -> lookback scan (+dis) -> CSR fill
    k_deg_stats<<<DB + SB, 256, 0, stream>>>(ei, E, DB, deg_d, deg_s, x, N, statsX);
    k_scan_dis<<<SC, 256, 0, stream>>>(deg_d, deg_s, N, E, rowptr, cursor, dis, aggr, flag);
    k_fill<<<FB, 256, 0, stream>>>(ei, E, cursor, eidx);

    // feature layer: gemm<128> (BN fold fused; stats-of-output -> replica slots)
    k_gemm<128, true, false, true, true><<<gG, 256, 0, stream>>>(
        x, Wfeat, statsX, bnfg, bnfb, bfeat, nullptr, n_inv, (void*)bufA, N, statsL);

    // GCN layers
    for (int l = 0; l < L; ++l) {
        k_gemm<64, false, true, false, false><<<gG, 256, 0, stream>>>(
            bufA, Ws + (size_t)l * HID * HID, statsL + (size_t)l * NREP * 128,
            bng + (size_t)l * HID, bnb + (size_t)l * HID,
            nullptr, dis, n_inv, (void*)bufB, N, nullptr);
        if (l < L - 1) {
            k_agg<false><<<gA, 256, 0, stream>>>(bufB, rowptr, eidx, dis, bs + (size_t)l * HID,
                                                 bufA, N, statsL + (size_t)(l + 1) * NREP * 128,
                                                 nullptr, nullptr);
        } else {
            k_agg<true><<<gA, 256, 0, stream>>>(bufB, rowptr, eidx, dis, bs + (size_t)l * HID,
                                                nullptr, N, nullptr, batch, out);
        }
    }
}

// Round 5
// 260.359 us; speedup vs baseline: 1.3266x; 1.3266x over previous
//
#include <hip/hip_runtime.h>
#include <math.h>

#define HID 64
#define BN_EPS 1e-5f
#define NREP 64   // stats replica slots (contention: nblocks/NREP per address)

typedef unsigned int uint;
typedef unsigned short ushort;

// ============ bf16 helpers ============

__device__ inline uint bf16pk(float a, float b) {
    uint ua = __builtin_bit_cast(uint, a);
    ua += 0x7fff + ((ua >> 16) & 1);
    uint ub = __builtin_bit_cast(uint, b);
    ub += 0x7fff + ((ub >> 16) & 1);
    return (ua >> 16) | (ub & 0xffff0000u);
}
__device__ inline float bfl(uint v) { return __builtin_bit_cast(float, v << 16); }
__device__ inline float bfh(uint v) { return __builtin_bit_cast(float, v & 0xffff0000u); }

// ============ K1: fused hist+scan (last-block pattern) ∥ x-stats stage-1 ============
// blocks [0,HB): LDS radix hist over dst>>8 / src>>8 -> bucket atomics (HB contenders/addr)
//               last-arriving block scans buckets -> bbase/cursor, rowptr[N]=E
// blocks [HB,..): BN stats stage-1 over x -> replica slots of statsX

__global__ __launch_bounds__(256) void k_hist_scan_stats(
        const int* __restrict__ ei, int E, int NB, int N, int HB,
        int* __restrict__ bcnt_d, int* __restrict__ bcnt_s, int* __restrict__ done,
        int* __restrict__ bbase_d, int* __restrict__ cursor_d,
        int* __restrict__ bbase_s, int* __restrict__ cursor_s,
        int* __restrict__ rowptr,
        const float* __restrict__ X, int n, float* __restrict__ stats) {
    __shared__ __align__(16) char smemraw[8192];
    __shared__ int lastFlag;
    int t = threadIdx.x;
    if ((int)blockIdx.x < HB) {
        int* hd = (int*)smemraw;
        int* hs = hd + 256;
        hd[t] = 0; hs[t] = 0;
        __syncthreads();
        for (int e = blockIdx.x * 256 + t; e < E; e += HB * 256) {
            int src = ei[e], dst = ei[E + e];
            atomicAdd(&hs[src >> 8], 1);
            atomicAdd(&hd[dst >> 8], 1);
        }
        __syncthreads();
        if (t < NB) {
            if (hd[t]) atomicAdd(&bcnt_d[t], hd[t]);
            if (hs[t]) atomicAdd(&bcnt_s[t], hs[t]);
        }
        __threadfence();
        __syncthreads();
        if (t == 0) lastFlag = (atomicAdd(done, 1) == HB - 1);
        __syncthreads();
        if (!lastFlag) return;
        // last block: coherent reads via atomic RMW, then double scan (reuse hd/hs)
        int v = (t < NB) ? atomicAdd(&bcnt_d[t], 0) : 0;
        hd[t] = v; __syncthreads();
        for (int s = 1; s < 256; s <<= 1) { int u = (t >= s) ? hd[t - s] : 0; __syncthreads(); hd[t] += u; __syncthreads(); }
        int excl = hd[t] - v;
        if (t <= NB) bbase_d[t] = excl;
        if (t < NB) cursor_d[t] = excl;
        if (t == 0) rowptr[N] = E;
        __syncthreads();
        v = (t < NB) ? atomicAdd(&bcnt_s[t], 0) : 0;
        hs[t] = v; __syncthreads();
        for (int s = 1; s < 256; s <<= 1) { int u = (t >= s) ? hs[t - s] : 0; __syncthreads(); hs[t] += u; __syncthreads(); }
        excl = hs[t] - v;
        if (t <= NB) bbase_s[t] = excl;
        if (t < NB) cursor_s[t] = excl;
    } else {
        // BN stats stage-1 over x [n,128] -> replica slot (bid & 63): [0..127]=sum, [128..255]=sumsq
        int b = blockIdx.x - HB;
        int SB = gridDim.x - HB;
        float4* shs = (float4*)smemraw;     // 256 float4 = 4KB
        float4* shq = shs + 256;            // 4KB more
        int c4 = t & 31, rsub = t >> 5;
        float4 s = make_float4(0.f, 0.f, 0.f, 0.f);
        float4 q = make_float4(0.f, 0.f, 0.f, 0.f);
        for (int r = b * 8 + rsub; r < n; r += SB * 8) {
            float4 v = ((const float4*)X)[(size_t)r * 32 + c4];
            s.x += v.x; s.y += v.y; s.z += v.z; s.w += v.w;
            q.x = fmaf(v.x, v.x, q.x); q.y = fmaf(v.y, v.y, q.y);
            q.z = fmaf(v.z, v.z, q.z); q.w = fmaf(v.w, v.w, q.w);
        }
        shs[t] = s; shq[t] = q;
        __syncthreads();
        if (rsub == 0) {
            #pragma unroll
            for (int k = 1; k < 8; k++) {
                float4 a = shs[t + k * 32], bq = shq[t + k * 32];
                s.x += a.x; s.y += a.y; s.z += a.z; s.w += a.w;
                q.x += bq.x; q.y += bq.y; q.z += bq.z; q.w += bq.w;
            }
            float* sb = stats + ((int)blockIdx.x & (NREP - 1)) * 256;
            atomicAdd(&sb[4 * t + 0], s.x); atomicAdd(&sb[4 * t + 1], s.y);
            atomicAdd(&sb[4 * t + 2], s.z); atomicAdd(&sb[4 * t + 3], s.w);
            atomicAdd(&sb[128 + 4 * t + 0], q.x); atomicAdd(&sb[128 + 4 * t + 1], q.y);
            atomicAdd(&sb[128 + 4 * t + 2], q.z); atomicAdd(&sb[128 + 4 * t + 3], q.w);
        }
    }
}

// ============ GEMM body (device fn) with fused BN-fold prologue (replica-summed
//              stats) + optional replica-atomic stats epilogue ============

template <int K, bool RELU, bool DIS, bool STATS, bool HASB>
__device__ __forceinline__ void gemm_body(const float* __restrict__ X, const float* __restrict__ W,
                                          const float* __restrict__ stats,
                                          const float* __restrict__ gamma, const float* __restrict__ beta,
                                          const float* __restrict__ bias0, const float* __restrict__ dis,
                                          float n_inv, void* __restrict__ out, int n,
                                          float* __restrict__ sout, int bx) {
    constexpr int KC = 64;
    constexpr int XS = 68;
    __shared__ float Xs[KC * XS];
    __shared__ float Wsm[KC * HID];
    __shared__ float As[128], Cs[128];

    int t = threadIdx.x;
    int tx = t & 15, ty = t >> 4;
    int row0 = bx * 64;

    if (t < K) {
        // sum the NREP replica slots (L2-hot; stride 2K floats per replica)
        float ssum = 0.f, qsum = 0.f;
        const float* sp = stats + t;
        #pragma unroll 8
        for (int r = 0; r < NREP; ++r) {
            ssum += sp[(size_t)r * 2 * K];
            qsum += sp[(size_t)r * 2 * K + K];
        }
        float mu = ssum * n_inv;
        float var = qsum * n_inv - mu * mu;
        float a = gamma[t] * rsqrtf(var + BN_EPS);
        As[t] = a;
        Cs[t] = beta[t] - mu * a;
    }
    __syncthreads();

    float acc[4][4];
    #pragma unroll
    for (int i = 0; i < 4; i++)
        #pragma unroll
        for (int j = 0; j < 4; j++) acc[i][j] = 0.f;
    float4 bp = make_float4(0.f, 0.f, 0.f, 0.f);

    for (int kc = 0; kc < K; kc += KC) {
        #pragma unroll
        for (int it = 0; it < 4; ++it) {
            int id = t + 256 * it;
            int r = id >> 4, c4 = id & 15;
            float4 v = make_float4(0.f, 0.f, 0.f, 0.f);
            if (row0 + r < n) v = *(const float4*)(X + (size_t)(row0 + r) * K + kc + 4 * c4);
            int kk = 4 * c4;
            Xs[(kk + 0) * XS + r] = v.x;
            Xs[(kk + 1) * XS + r] = v.y;
            Xs[(kk + 2) * XS + r] = v.z;
            Xs[(kk + 3) * XS + r] = v.w;
        }
        {
            const float4* wsrc = (const float4*)(W + (size_t)kc * HID);
            #pragma unroll
            for (int it = 0; it < 4; ++it) {
                int id = t + 256 * it;
                int kl = id >> 4;
                float4 raw = wsrc[id];
                float a = As[kc + kl], c = Cs[kc + kl];
                float4 sc;
                sc.x = a * raw.x; sc.y = a * raw.y; sc.z = a * raw.z; sc.w = a * raw.w;
                ((float4*)Wsm)[id] = sc;
                bp.x = fmaf(c, raw.x, bp.x);
                bp.y = fmaf(c, raw.y, bp.y);
                bp.z = fmaf(c, raw.z, bp.z);
                bp.w = fmaf(c, raw.w, bp.w);
            }
        }
        __syncthreads();
        #pragma unroll 8
        for (int k = 0; k < KC; ++k) {
            float4 xv = *(const float4*)&Xs[k * XS + 4 * ty];
            float4 wv = *(const float4*)&Wsm[k * HID + 4 * tx];
            acc[0][0] = fmaf(xv.x, wv.x, acc[0][0]);
            acc[0][1] = fmaf(xv.x, wv.y, acc[0][1]);
            acc[0][2] = fmaf(xv.x, wv.z, acc[0][2]);
            acc[0][3] = fmaf(xv.x, wv.w, acc[0][3]);
            acc[1][0] = fmaf(xv.y, wv.x, acc[1][0]);
            acc[1][1] = fmaf(xv.y, wv.y, acc[1][1]);
            acc[1][2] = fmaf(xv.y, wv.z, acc[1][2]);
            acc[1][3] = fmaf(xv.y, wv.w, acc[1][3]);
            acc[2][0] = fmaf(xv.z, wv.x, acc[2][0]);
            acc[2][1] = fmaf(xv.z, wv.y, acc[2][1]);
            acc[2][2] = fmaf(xv.z, wv.z, acc[2][2]);
            acc[2][3] = fmaf(xv.z, wv.w, acc[2][3]);
            acc[3][0] = fmaf(xv.w, wv.x, acc[3][0]);
            acc[3][1] = fmaf(xv.w, wv.y, acc[3][1]);
            acc[3][2] = fmaf(xv.w, wv.z, acc[3][2]);
            acc[3][3] = fmaf(xv.w, wv.w, acc[3][3]);
        }
        __syncthreads();
    }

    {
        float* redb = Xs + 2048;
        *(float4*)&redb[ty * 64 + 4 * tx] = bp;
        __syncthreads();
        if (t < 64) {
            float s = 0.f;
            #pragma unroll
            for (int k = 0; k < 16; ++k) s += redb[k * 64 + t];
            Xs[3072 + t] = s + (HASB ? bias0[t] : 0.f);
        }
        __syncthreads();
    }
    float4 bv = *(const float4*)&Xs[3072 + 4 * tx];

    float4 cs = make_float4(0.f, 0.f, 0.f, 0.f);
    float4 cq = make_float4(0.f, 0.f, 0.f, 0.f);
    #pragma unroll
    for (int i = 0; i < 4; ++i) {
        int row = row0 + 4 * ty + i;
        bool valid = row < n;
        float vx = acc[i][0] + bv.x, vy = acc[i][1] + bv.y;
        float vz = acc[i][2] + bv.z, vw = acc[i][3] + bv.w;
        if constexpr (DIS) {
            if (valid) {
                float d = dis[row];
                uint2 pk;
                pk.x = bf16pk(vx * d, vy * d);
                pk.y = bf16pk(vz * d, vw * d);
                *(uint2*)((ushort*)out + (size_t)row * HID + 4 * tx) = pk;
            }
        } else {
            float4 v;
            v.x = RELU ? fmaxf(vx, 0.f) : vx;
            v.y = RELU ? fmaxf(vy, 0.f) : vy;
            v.z = RELU ? fmaxf(vz, 0.f) : vz;
            v.w = RELU ? fmaxf(vw, 0.f) : vw;
            if (valid) {
                *(float4*)((float*)out + (size_t)row * HID + 4 * tx) = v;
                if constexpr (STATS) {
                    cs.x += v.x; cs.y += v.y; cs.z += v.z; cs.w += v.w;
                    cq.x = fmaf(v.x, v.x, cq.x); cq.y = fmaf(v.y, v.y, cq.y);
                    cq.z = fmaf(v.z, v.z, cq.z); cq.w = fmaf(v.w, v.w, cq.w);
                }
            }
        }
    }
    if constexpr (STATS) {
        __syncthreads();
        float* reds = Xs;
        float* redq = Xs + 1024;
        *(float4*)&reds[ty * 64 + 4 * tx] = cs;
        *(float4*)&redq[ty * 64 + 4 * tx] = cq;
        __syncthreads();
        if (t < 64) {
            float s = 0.f, q = 0.f;
            #pragma unroll
            for (int k = 0; k < 16; ++k) { s += reds[k * 64 + t]; q += redq[k * 64 + t]; }
            float* sb = sout + ((int)bx & (NREP - 1)) * 128;
            atomicAdd(&sb[t], s);
            atomicAdd(&sb[64 + t], q);
        }
    }
}

template <int K, bool RELU, bool DIS, bool STATS, bool HASB>
__global__ __launch_bounds__(256) void k_gemm(const float* __restrict__ X, const float* __restrict__ W,
                                              const float* __restrict__ stats,
                                              const float* __restrict__ gamma, const float* __restrict__ beta,
                                              const float* __restrict__ bias0, const float* __restrict__ dis,
                                              float n_inv, void* __restrict__ out, int n,
                                              float* __restrict__ sout) {
    gemm_body<K, RELU, DIS, STATS, HASB>(X, W, stats, gamma, beta, bias0, dis, n_inv, out, n, sout,
                                         (int)blockIdx.x);
}

// ============ K2: scatter edges into buckets ∥ gemm<128> (feature layer) ============
// blocks [0,SCB): scatter (needs cursors from K1); blocks [SCB,..): gemm128 (needs statsX from K1)

__global__ __launch_bounds__(256) void k_scatter_gemm(
        const int* __restrict__ ei, int E, int NB, int SCB,
        int* __restrict__ cursor_d, int* __restrict__ cursor_s,
        uint* __restrict__ bedge, int* __restrict__ bsrc,
        const float* __restrict__ X, const float* __restrict__ W,
        const float* __restrict__ stats,
        const float* __restrict__ gamma, const float* __restrict__ beta,
        const float* __restrict__ bias0,
        float n_inv, void* __restrict__ out, int n, float* __restrict__ sout) {
    int t = threadIdx.x;
    if ((int)blockIdx.x < SCB) {
        __shared__ int hd[256], hs[256], curd[256], curs[256];
        int chunk = (E + SCB - 1) / SCB;
        int e0 = blockIdx.x * chunk;
        int e1 = min(e0 + chunk, E);
        if (t < NB) { hd[t] = 0; hs[t] = 0; }
        __syncthreads();
        for (int e = e0 + t; e < e1; e += 256) {
            int src = ei[e], dst = ei[E + e];
            atomicAdd(&hd[dst >> 8], 1);
            atomicAdd(&hs[src >> 8], 1);
        }
        __syncthreads();
        if (t < NB) {
            curd[t] = hd[t] ? atomicAdd(&cursor_d[t], hd[t]) : 0;
            curs[t] = hs[t] ? atomicAdd(&cursor_s[t], hs[t]) : 0;
        }
        __syncthreads();
        for (int e = e0 + t; e < e1; e += 256) {
            int src = ei[e], dst = ei[E + e];
            int pd = atomicAdd(&curd[dst >> 8], 1);
            bedge[pd] = ((uint)(dst & 255) << 16) | (uint)src;   // N < 65536
            int ps = atomicAdd(&curs[src >> 8], 1);
            bsrc[ps] = src;
        }
    } else {
        gemm_body<128, true, false, true, true>(X, W, stats, gamma, beta, bias0, nullptr,
                                                n_inv, out, n, sout, (int)blockIdx.x - SCB);
    }
}

// ============ K3: fused: blocks [0,NB) dst-CSR; [NB,2NB) outdeg->dis ============

__global__ __launch_bounds__(256) void k_build_csr_outdeg(
        const uint* __restrict__ bedge, const int* __restrict__ bbase_d,
        const int* __restrict__ bsrc, const int* __restrict__ bbase_s,
        int N, int NB,
        int* __restrict__ rowptr, int* __restrict__ eidx, float* __restrict__ dis) {
    __shared__ int h[256], off[256], cur[256];
    int t = threadIdx.x, b = blockIdx.x;
    if (b < NB) {
        int base = bbase_d[b], end = bbase_d[b + 1];
        h[t] = 0; __syncthreads();
        for (int p = base + t; p < end; p += 256)
            atomicAdd(&h[(int)(bedge[p] >> 16) & 255], 1);
        __syncthreads();
        off[t] = h[t]; __syncthreads();
        for (int s = 1; s < 256; s <<= 1) { int u = (t >= s) ? off[t - s] : 0; __syncthreads(); off[t] += u; __syncthreads(); }
        int excl = off[t] - h[t];
        int node = (b << 8) + t;
        if (node <= N) rowptr[node] = base + excl;
        cur[t] = excl; __syncthreads();
        for (int p = base + t; p < end; p += 256) {
            uint be = bedge[p];
            int bin = (int)(be >> 16) & 255;
            int pos = atomicAdd(&cur[bin], 1);
            eidx[base + pos] = (int)(be & 0xffffu);
        }
    } else {
        int b2 = b - NB;
        int base = bbase_s[b2], end = bbase_s[b2 + 1];
        h[t] = 0; __syncthreads();
        for (int p = base + t; p < end; p += 256) atomicAdd(&h[bsrc[p] & 255], 1);
        __syncthreads();
        int node = (b2 << 8) + t;
        if (node < N) dis[node] = rsqrtf((float)(h[t] + 1));
    }
}

// ============ aggregation: 8 nodes/block, per node 4 edge-slots x 8 feature-lanes,
// 16B uint4 gathers, branch-free batches of 4 edges per slot (4 gathers in flight
// per lane; masked lanes gather the cache-hot self row with weight 0).
// !POOL: writes fp32 out rows + replica-atomic BN stats. POOL: fuses global_add_pool. ============

template <bool POOL>
__global__ __launch_bounds__(256) void k_agg(const ushort* __restrict__ s, const int* __restrict__ rowptr,
                                             const int* __restrict__ eidx, const float* __restrict__ dis,
                                             const float* __restrict__ bias, float* __restrict__ out, int n,
                                             float* __restrict__ sout, const int* __restrict__ batch,
                                             float* __restrict__ pool_out) {
    __shared__ float shs[8 * 64];
    __shared__ float shq[8 * 64];
    __shared__ int ib[8];
    int t = threadIdx.x;
    int nl = t >> 5;          // node slot in block (0..7); 2 nodes per wave
    int li = t & 31;
    int slot = li >> 3;       // edge slot 0..3
    int c = li & 7;           // uint4 column -> features 8c..8c+7
    int i = blockIdx.x * 8 + nl;
    const uint4* sp4 = (const uint4*)s;
    float a[8];
    #pragma unroll
    for (int k = 0; k < 8; ++k) a[k] = 0.f;
    bool valid = i < n;
    if (valid) {
        int qe = rowptr[i + 1];
        int q = rowptr[i] + slot;
        while (q < qe) {
            // branch-free batch of 4 edges for this slot (stride 4 between slots)
            int qm = qe - 1;
            int q1 = q + 4, q2 = q + 8, q3 = q + 12;
            bool p1 = q1 < qe, p2 = q2 < qe, p3 = q3 < qe;
            int j0 = eidx[q];
            int j1 = eidx[min(q1, qm)];
            int j2 = eidx[min(q2, qm)];
            int j3 = eidx[min(q3, qm)];
            if (!p1) j1 = i;           // masked -> self row (L1-hot), weight 0
            if (!p2) j2 = i;
            if (!p3) j3 = i;
            uint4 v0 = sp4[(size_t)j0 * 8 + c];
            uint4 v1 = sp4[(size_t)j1 * 8 + c];
            uint4 v2 = sp4[(size_t)j2 * 8 + c];
            uint4 v3 = sp4[(size_t)j3 * 8 + c];
            float m1 = p1 ? 1.f : 0.f;
            float m2 = p2 ? 1.f : 0.f;
            float m3 = p3 ? 1.f : 0.f;
            q += 16;
            a[0] += bfl(v0.x); a[1] += bfh(v0.x);
            a[2] += bfl(v0.y); a[3] += bfh(v0.y);
            a[4] += bfl(v0.z); a[5] += bfh(v0.z);
            a[6] += bfl(v0.w); a[7] += bfh(v0.w);
            a[0] = fmaf(m1, bfl(v1.x), a[0]); a[1] = fmaf(m1, bfh(v1.x), a[1]);
            a[2] = fmaf(m1, bfl(v1.y), a[2]); a[3] = fmaf(m1, bfh(v1.y), a[3]);
            a[4] = fmaf(m1, bfl(v1.z), a[4]); a[5] = fmaf(m1, bfh(v1.z), a[5]);
            a[6] = fmaf(m1, bfl(v1.w), a[6]); a[7] = fmaf(m1, bfh(v1.w), a[7]);
            a[0] = fmaf(m2, bfl(v2.x), a[0]); a[1] = fmaf(m2, bfh(v2.x), a[1]);
            a[2] = fmaf(m2, bfl(v2.y), a[2]); a[3] = fmaf(m2, bfh(v2.y), a[3]);
            a[4] = fmaf(m2, bfl(v2.z), a[4]); a[5] = fmaf(m2, bfh(v2.z), a[5]);
            a[6] = fmaf(m2, bfl(v2.w), a[6]); a[7] = fmaf(m2, bfh(v2.w), a[7]);
            a[0] = fmaf(m3, bfl(v3.x), a[0]); a[1] = fmaf(m3, bfh(v3.x), a[1]);
            a[2] = fmaf(m3, bfl(v3.y), a[2]); a[3] = fmaf(m3, bfh(v3.y), a[3]);
            a[4] = fmaf(m3, bfl(v3.z), a[4]); a[5] = fmaf(m3, bfh(v3.z), a[5]);
            a[6] = fmaf(m3, bfl(v3.w), a[6]); a[7] = fmaf(m3, bfh(v3.w), a[7]);
        }
    }
    // reduce across the 4 edge slots (lanes differ in bits 3,4 -> stays within node group)
    #pragma unroll
    for (int k = 0; k < 8; ++k) a[k] += __shfl_xor(a[k], 8);
    #pragma unroll
    for (int k = 0; k < 8; ++k) a[k] += __shfl_xor(a[k], 16);

    if (li < 8) {
        float r[8];
        if (valid) {
            uint4 v = sp4[(size_t)i * 8 + c];   // self-loop contribution
            a[0] += bfl(v.x); a[1] += bfh(v.x);
            a[2] += bfl(v.y); a[3] += bfh(v.y);
            a[4] += bfl(v.z); a[5] += bfh(v.z);
            a[6] += bfl(v.w); a[7] += bfh(v.w);
            float d = dis[i];
            float4 b0 = *(const float4*)(bias + 8 * c);
            float4 b1 = *(const float4*)(bias + 8 * c + 4);
            r[0] = fmaxf(fmaf(d, a[0], b0.x), 0.f);
            r[1] = fmaxf(fmaf(d, a[1], b0.y), 0.f);
            r[2] = fmaxf(fmaf(d, a[2], b0.z), 0.f);
            r[3] = fmaxf(fmaf(d, a[3], b0.w), 0.f);
            r[4] = fmaxf(fmaf(d, a[4], b1.x), 0.f);
            r[5] = fmaxf(fmaf(d, a[5], b1.y), 0.f);
            r[6] = fmaxf(fmaf(d, a[6], b1.z), 0.f);
            r[7] = fmaxf(fmaf(d, a[7], b1.w), 0.f);
            if constexpr (!POOL) {
                *(float4*)(out + (size_t)i * HID + 8 * c)     = make_float4(r[0], r[1], r[2], r[3]);
                *(float4*)(out + (size_t)i * HID + 8 * c + 4) = make_float4(r[4], r[5], r[6], r[7]);
            }
        } else {
            #pragma unroll
            for (int k = 0; k < 8; ++k) r[k] = 0.f;
        }
        #pragma unroll
        for (int k = 0; k < 8; ++k) shs[nl * 64 + 8 * c + k] = r[k];
        if constexpr (!POOL) {
            #pragma unroll
            for (int k = 0; k < 8; ++k) shq[nl * 64 + 8 * c + k] = r[k] * r[k];
        }
    }
    if constexpr (POOL) {
        if (li == 0) ib[nl] = valid ? batch[i] : -1;
    }
    __syncthreads();
    if (t < 64) {
        if constexpr (!POOL) {
            float ss = 0.f, qq = 0.f;
            #pragma unroll
            for (int k = 0; k < 8; ++k) { ss += shs[k * 64 + t]; qq += shq[k * 64 + t]; }
            float* sb = sout + ((int)blockIdx.x & (NREP - 1)) * 128;
            atomicAdd(&sb[t], ss);
            atomicAdd(&sb[64 + t], qq);
        } else {
            // batch is sorted -> run-length merge across the 8 nodes, then few atomics
            int g = ib[0];
            float run = shs[t];
            #pragma unroll
            for (int k = 1; k < 8; ++k) {
                int gk = ib[k];
                float v = shs[k * 64 + t];
                if (gk == g) {
                    run += v;
                } else {
                    if (g >= 0) atomicAdd(&pool_out[(size_t)g * HID + t], run);
                    g = gk; run = v;
                }
            }
            if (g >= 0) atomicAdd(&pool_out[(size_t)g * HID + t], run);
        }
    }
}

// ============ driver ============

extern "C" void kernel_launch(void* const* d_in, const int* in_sizes, int n_in,
                              void* d_out, int out_size, void* d_ws, size_t ws_size,
                              hipStream_t stream) {
    const float* x     = (const float*)d_in[0];
    const int*   ei    = (const int*)d_in[1];
    const int*   batch = (const int*)d_in[2];
    const float* bnfg  = (const float*)d_in[3];
    const float* bnfb  = (const float*)d_in[4];
    const float* Wfeat = (const float*)d_in[5];
    const float* bfeat = (const float*)d_in[6];
    const float* bng   = (const float*)d_in[7];
    const float* bnb   = (const float*)d_in[8];
    const float* Ws    = (const float*)d_in[9];
    const float* bs    = (const float*)d_in[10];
    float* out = (float*)d_out;

    const int N   = in_sizes[2];
    const int E   = in_sizes[1] / 2;
    const int L   = in_sizes[9] / (HID * HID);
    const int NB  = (N + 255) >> 8;
    const int HB  = 128;                    // hist blocks (contenders/address in final adds)
    const int SB  = 512;                    // stats<128> stage-1 blocks
    const int SCB = 256;                    // scatter blocks
    const int gG  = (N + 63) / 64;          // gemm blocks
    const int gA  = (N + 7) / 8;            // agg blocks
    const float n_inv = 1.f / (float)N;

    char* w = (char*)d_ws;
    auto alloc = [&](size_t bytes) { char* p = w; w += (bytes + 255) & ~(size_t)255; return p; };
    // ---- zeroed prefix ----
    int*   bcnt_d = (int*)alloc(256 * 4);
    int*   bcnt_s = (int*)alloc(256 * 4);
    int*   done   = (int*)alloc(256);
    // statsX: NREP replicas x (sum128, sq128) for the x BN
    float* statsX = (float*)alloc((size_t)NREP * 256 * 4);
    // statsL: 3 layer slots, each NREP replicas x (sum64, sq64)
    float* statsL = (float*)alloc((size_t)3 * NREP * 128 * 4);
    size_t zero_bytes = (size_t)(w - (char*)d_ws);
    // ---- rest ----
    int*   bbase_d  = (int*)alloc(257 * 4);
    int*   cursor_d = (int*)alloc(256 * 4);
    int*   bbase_s  = (int*)alloc(257 * 4);
    int*   cursor_s = (int*)alloc(256 * 4);
    int*   rowptr   = (int*)alloc(((size_t)N + 1) * 4);
    int*   eidx     = (int*)alloc((size_t)E * 4);
    float* dis      = (float*)alloc((size_t)N * 4);
    float* bufA     = (float*)alloc((size_t)N * HID * 4);
    ushort* bufB    = (ushort*)alloc((size_t)N * HID * 2);
    uint*  bedge    = (uint*)alloc((size_t)E * 4);   // NOT aliased: written concurrently with bufA
    int*   bsrc     = (int*)alloc((size_t)E * 4);

    hipMemsetAsync(d_ws, 0, zero_bytes, stream);
    hipMemsetAsync(d_out, 0, (size_t)out_size * sizeof(float), stream);  // pool accumulates atomically

    // K1: hist+scan (last-block pattern) ∥ x-stats stage-1
    k_hist_scan_stats<<<HB + SB, 256, 0, stream>>>(ei, E, NB, N, HB, bcnt_d, bcnt_s, done,
                                                   bbase_d, cursor_d, bbase_s, cursor_s, rowptr,
                                                   x, N, statsX);
    // K2: scatter into buckets ∥ gemm<128> feature layer (stats-of-output -> statsL slot 0)
    k_scatter_gemm<<<SCB + gG, 256, 0, stream>>>(ei, E, NB, SCB, cursor_d, cursor_s, bedge, bsrc,
                                                 x, Wfeat, statsX, bnfg, bnfb, bfeat,
                                                 n_inv, (void*)bufA, N, statsL);
    // K3: dst-CSR build + outdeg->dis
    k_build_csr_outdeg<<<2 * NB, 256, 0, stream>>>(bedge, bbase_d, bsrc, bbase_s, N, NB,
                                                   rowptr, eidx, dis);

    // GCN layers
    for (int l = 0; l < L; ++l) {
        k_gemm<64, false, true, false, false><<<gG, 256, 0, stream>>>(
            bufA, Ws + (size_t)l * HID * HID, statsL + (size_t)l * NREP * 128,
            bng + (size_t)l * HID, bnb + (size_t)l * HID,
            nullptr, dis, n_inv, (void*)bufB, N, nullptr);
        if (l < L - 1) {
            k_agg<false><<<gA, 256, 0, stream>>>(bufB, rowptr, eidx, dis, bs + (size_t)l * HID,
                                                 bufA, N, statsL + (size_t)(l + 1) * NREP * 128,
                                                 nullptr, nullptr);
        } else {
            k_agg<true><<<gA, 256, 0, stream>>>(bufB, rowptr, eidx, dis, bs + (size_t)l * HID,
                                                nullptr, N, nullptr, batch, out);
        }
    }
}